// Round 6
// baseline (161.223 us; speedup 1.0000x reference)
//
#include <hip/hip_runtime.h>

#define DD 8
#define HW 16384
#define KK 256
#define NPIX 524288
#define NBLK 2048                      // 256 pixels per block, 1 px/thread

#define Y_OFF    4194304UL             // B*D*H*W
#define REP_OFF  4718592UL             // + B*H*W
#define LOSS_OFF 138936320UL           // + B*H*W*K

typedef float f4 __attribute__((ext_vector_type(4)));

// ---------------- prep: zero hist + precompute ||c||^2 ----------------
__global__ __launch_bounds__(256) void vq_prep_kernel(
    const float* __restrict__ cb, float* __restrict__ c2t, int* __restrict__ hist)
{
    const int k = threadIdx.x;
    const float* c = cb + k*DD;
    c2t[k] = ((c[0]*c[0] + c[1]*c[1]) + (c[2]*c[2] + c[3]*c[3]))
           + ((c[4]*c[4] + c[5]*c[5]) + (c[6]*c[6] + c[7]*c[7]));
    hist[k] = 0;
}

// ---- fused: argmax with zero-fill streamed INSIDE the k-loop + 1.0 scatter ----
__global__ __launch_bounds__(256) void vq_fused_kernel(
    const float* __restrict__ q, const float* __restrict__ cb,
    const float* __restrict__ c2t,
    float* __restrict__ emb, float* __restrict__ yf, float* __restrict__ rep,
    int* __restrict__ hist, float* __restrict__ partial)
{
    __shared__ int   shist[KK];
    __shared__ float swred[4];

    const int tid = threadIdx.x;
    shist[tid] = 0;

    const int pixBase = blockIdx.x << 8;
    const int b   = pixBase >> 14;          // image index (block within one image)
    const int hwB = pixBase & (HW - 1);
    const int hw  = hwB + tid;
    const float* qb = q + (size_t)b * (DD*HW);

    float xs[DD];
#pragma unroll
    for (int d = 0; d < DD; ++d) xs[d] = qb[d*HW + hw];
    const float xn = ((xs[0]*xs[0] + xs[1]*xs[1]) + (xs[2]*xs[2] + xs[3]*xs[3]))
                   + ((xs[4]*xs[4] + xs[5]*xs[5]) + (xs[6]*xs[6] + xs[7]*xs[7]));

    // block's rep region: 256 rows x 1 KB = 256 KB; iter k zeroes row k
    float* repz = rep + (size_t)pixBase * KK + tid;

    // t = (x2 - 2xc) + c2 with strict <  ==  reference -0.5*t with strict >
    float best = 3.4e38f;
    int   yb   = 0;
#pragma unroll 4
    for (int k = 0; k < KK; ++k) {
        // lane-invariant addresses -> s_load (SMEM pipe), no LDS, no vector loads
        const f4 c01 = *(const f4*)(cb + (k << 3));
        const f4 c23 = *(const f4*)(cb + (k << 3) + 4);
        const float c2k = c2t[k];
        float dot = 0.f;
        dot = fmaf(xs[0], c01.x, dot);
        dot = fmaf(xs[1], c01.y, dot);
        dot = fmaf(xs[2], c01.z, dot);
        dot = fmaf(xs[3], c01.w, dot);
        dot = fmaf(xs[4], c23.x, dot);
        dot = fmaf(xs[5], c23.y, dot);
        dot = fmaf(xs[6], c23.z, dot);
        dot = fmaf(xs[7], c23.w, dot);
        const float t = (xn - 2.0f*dot) + c2k;
        if (t < best) { best = t; yb = k; }   // first index wins ties
        // stream the one-hot zero-fill under the compute: row k, dword tid
        repz[k << 8] = 0.0f;
    }

    // per-pixel outputs: emb (gather codebook[yb]), y, err
    float err;
    {
        const f4 cy01 = *(const f4*)(cb + (yb << 3));
        const f4 cy23 = *(const f4*)(cb + (yb << 3) + 4);
        float cyv[DD] = {cy01.x, cy01.y, cy01.z, cy01.w,
                         cy23.x, cy23.y, cy23.z, cy23.w};
        float e = 0.f;
        float* eb = emb + (size_t)b * (DD*HW) + hw;
#pragma unroll
        for (int d = 0; d < DD; ++d) {
            eb[d*HW] = cyv[d];
            const float dd = cyv[d] - xs[d];
            e = fmaf(dd, dd, e);
        }
        err = e;
        yf[pixBase + tid] = (float)yb;
        atomicAdd(&shist[yb], 1);
    }

    // deterministic wave reduction of err (finalized before the barrier)
#pragma unroll
    for (int off = 32; off; off >>= 1)
        err += __shfl_down(err, off, 64);
    if ((tid & 63) == 0) swred[tid >> 6] = err;

    __syncthreads();   // vmcnt(0) drained before s_barrier: all zero stores
                       // complete at L2 before any wave's 1.0 scatter below

    // scatter the ones: my row = tid, column = yb
    rep[(size_t)(pixBase + tid) * KK + yb] = 1.0f;

    if (tid == 0)
        partial[blockIdx.x] = (swred[0] + swred[1]) + (swred[2] + swred[3]);
    atomicAdd(&hist[tid], shist[tid]);   // shist complete after barrier above
}

// ---------------- finalize scalars ----------------
__global__ __launch_bounds__(256) void vq_final_kernel(
    const float* __restrict__ partial, const int* __restrict__ hist,
    float* __restrict__ outp)
{
    const int tid = threadIdx.x;
    __shared__ double sred[4];
    __shared__ double shy[4];

    double s = 0.0;
#pragma unroll
    for (int i = 0; i < 8; ++i) s += (double)partial[tid * 8 + i];
#pragma unroll
    for (int off = 32; off; off >>= 1)
        s += __shfl_down(s, off, 64);
    if ((tid & 63) == 0) sred[tid >> 6] = s;

    float c  = (float)hist[tid];
    float py = c * (1.0f / 524288.0f);
    double ht = (double)(py * log2f(py + 1e-10f));
#pragma unroll
    for (int off = 32; off; off >>= 1)
        ht += __shfl_down(ht, off, 64);
    if ((tid & 63) == 0) shy[tid >> 6] = ht;
    __syncthreads();

    if (tid == 0) {
        double S  = (sred[0] + sred[1]) + (sred[2] + sred[3]);
        double Hy = (shy[0]  + shy[1])  + (shy[2]  + shy[3]);
        // loss = 0.5*(0.25*S/4096 + S/4096) = 0.625 * S / 4096
        outp[0] = (float)(0.625 * S / 4096.0);
        outp[1] = (float)(-Hy);
        outp[2] = 0.0f;
    }
}

extern "C" void kernel_launch(void* const* d_in, const int* in_sizes, int n_in,
                              void* d_out, int out_size, void* d_ws, size_t ws_size,
                              hipStream_t stream)
{
    const float* q  = (const float*)d_in[0];
    const float* cb = (const float*)d_in[1];
    float* out = (float*)d_out;

    float* emb = out;                     // [B,D,H,W]
    float* yf  = out + Y_OFF;             // [B,H,W] as float
    float* rep = out + REP_OFF;           // [B,H,W,K]
    float* sc  = out + LOSS_OFF;          // loss, Hy, Hyx

    float* w       = (float*)d_ws;
    int*   hist    = (int*)w;             // 256 ints
    float* partial = w + 256;             // 2048 floats
    float* c2t     = w + 256 + 2048;      // 256 floats

    vq_prep_kernel<<<1, 256, 0, stream>>>(cb, c2t, hist);
    vq_fused_kernel<<<NBLK, 256, 0, stream>>>(q, cb, c2t, emb, yf, rep, hist, partial);
    vq_final_kernel<<<1, 256, 0, stream>>>(partial, hist, sc);
}

// Round 7
// 135.372 us; speedup vs baseline: 1.1910x; 1.1910x over previous
//
#include <hip/hip_runtime.h>

#define DD 8
#define HW 16384
#define KK 256
#define NPIX 524288
#define NBLK 2048                      // 256 pixels per block, 1 px/thread

#define Y_OFF    4194304UL             // B*D*H*W
#define REP_OFF  4718592UL             // + B*H*W
#define LOSS_OFF 138936320UL           // + B*H*W*K

typedef float f4 __attribute__((ext_vector_type(4)));

// ---------------- prep: zero hist + precompute ||c||^2 ----------------
__global__ __launch_bounds__(256) void vq_prep_kernel(
    const float* __restrict__ cb, float* __restrict__ c2t, int* __restrict__ hist)
{
    const int k = threadIdx.x;
    const float* c = cb + k*DD;
    c2t[k] = ((c[0]*c[0] + c[1]*c[1]) + (c[2]*c[2] + c[3]*c[3]))
           + ((c[4]*c[4] + c[5]*c[5]) + (c[6]*c[6] + c[7]*c[7]));
    hist[k] = 0;
}

// ---- fused: argmax with coalesced nt zero-fill streamed inside the k-loop ----
__global__ __launch_bounds__(256) void vq_fused_kernel(
    const float* __restrict__ q, const float* __restrict__ cb,
    const float* __restrict__ c2t,
    float* __restrict__ emb, float* __restrict__ yf, float* __restrict__ rep,
    int* __restrict__ hist, float* __restrict__ partial)
{
    __shared__ int   shist[KK];
    __shared__ float swred[4];

    const int tid  = threadIdx.x;
    const int wid  = tid >> 6;
    const int lane = tid & 63;
    shist[tid] = 0;

    const int pixBase = blockIdx.x << 8;
    const int b   = pixBase >> 14;          // image index (block within one image)
    const int hwB = pixBase & (HW - 1);
    const int hw  = hwB + tid;
    const float* qb = q + (size_t)b * (DD*HW);

    float xs[DD];
#pragma unroll
    for (int d = 0; d < DD; ++d) xs[d] = qb[d*HW + hw];
    const float xn = ((xs[0]*xs[0] + xs[1]*xs[1]) + (xs[2]*xs[2] + xs[3]*xs[3]))
                   + ((xs[4]*xs[4] + xs[5]*xs[5]) + (xs[6]*xs[6] + xs[7]*xs[7]));

    // wave wid owns rows [wid*64, wid*64+64) of the block's 256-row rep region;
    // at slot c the wave stores row wid*64+c as one coalesced 1 KB nt store.
    f4* rowp = (f4*)rep + (((size_t)(pixBase + (wid << 6))) << 6) + lane;
    const f4 z4 = {0.f, 0.f, 0.f, 0.f};

    // t = (x2 - 2xc) + c2 with strict <  ==  reference -0.5*t with strict >
    float best = 3.4e38f;
    int   yb   = 0;
    for (int c = 0; c < 64; ++c) {
#pragma unroll
        for (int j = 0; j < 4; ++j) {
            const int k = (c << 2) + j;
            // lane-invariant addresses -> s_load (SMEM pipe)
            const f4 c01 = *(const f4*)(cb + (k << 3));
            const f4 c23 = *(const f4*)(cb + (k << 3) + 4);
            const float c2k = c2t[k];
            float dot = 0.f;
            dot = fmaf(xs[0], c01.x, dot);
            dot = fmaf(xs[1], c01.y, dot);
            dot = fmaf(xs[2], c01.z, dot);
            dot = fmaf(xs[3], c01.w, dot);
            dot = fmaf(xs[4], c23.x, dot);
            dot = fmaf(xs[5], c23.y, dot);
            dot = fmaf(xs[6], c23.z, dot);
            dot = fmaf(xs[7], c23.w, dot);
            const float t = (xn - 2.0f*dot) + c2k;
            if (t < best) { best = t; yb = k; }   // first index wins ties
        }
        // stream the zero-fill under the compute (nt, coalesced, store-paced)
        __builtin_nontemporal_store(z4, rowp + ((size_t)c << 6));
    }

    // per-pixel outputs: emb (gather codebook[yb]), y, err
    float err;
    {
        const f4 cy01 = *(const f4*)(cb + (yb << 3));
        const f4 cy23 = *(const f4*)(cb + (yb << 3) + 4);
        float cyv[DD] = {cy01.x, cy01.y, cy01.z, cy01.w,
                         cy23.x, cy23.y, cy23.z, cy23.w};
        float e = 0.f;
        float* eb = emb + (size_t)b * (DD*HW) + hw;
#pragma unroll
        for (int d = 0; d < DD; ++d) {
            eb[d*HW] = cyv[d];
            const float dd = cyv[d] - xs[d];
            e = fmaf(dd, dd, e);
        }
        err = e;
        yf[pixBase + tid] = (float)yb;
        atomicAdd(&shist[yb], 1);
    }

    // wait for this wave's zero stores (row tid was written by THIS wave),
    // then overwrite the single element with 1.0 — same-address ordering via
    // retired-store + same-L2-channel FIFO.
    asm volatile("s_waitcnt vmcnt(0)" ::: "memory");
    rep[((size_t)(pixBase + tid) << 8) + yb] = 1.0f;

    // deterministic block reduction of err
#pragma unroll
    for (int off = 32; off; off >>= 1)
        err += __shfl_down(err, off, 64);
    if (lane == 0) swred[wid] = err;
    __syncthreads();
    if (tid == 0)
        partial[blockIdx.x] = (swred[0] + swred[1]) + (swred[2] + swred[3]);
    atomicAdd(&hist[tid], shist[tid]);   // shist complete after barrier above
}

// ---------------- finalize scalars ----------------
__global__ __launch_bounds__(256) void vq_final_kernel(
    const float* __restrict__ partial, const int* __restrict__ hist,
    float* __restrict__ outp)
{
    const int tid = threadIdx.x;
    __shared__ double sred[4];
    __shared__ double shy[4];

    double s = 0.0;
#pragma unroll
    for (int i = 0; i < 8; ++i) s += (double)partial[tid * 8 + i];
#pragma unroll
    for (int off = 32; off; off >>= 1)
        s += __shfl_down(s, off, 64);
    if ((tid & 63) == 0) sred[tid >> 6] = s;

    float c  = (float)hist[tid];
    float py = c * (1.0f / 524288.0f);
    double ht = (double)(py * log2f(py + 1e-10f));
#pragma unroll
    for (int off = 32; off; off >>= 1)
        ht += __shfl_down(ht, off, 64);
    if ((tid & 63) == 0) shy[tid >> 6] = ht;
    __syncthreads();

    if (tid == 0) {
        double S  = (sred[0] + sred[1]) + (sred[2] + sred[3]);
        double Hy = (shy[0]  + shy[1])  + (shy[2]  + shy[3]);
        // loss = 0.5*(0.25*S/4096 + S/4096) = 0.625 * S / 4096
        outp[0] = (float)(0.625 * S / 4096.0);
        outp[1] = (float)(-Hy);
        outp[2] = 0.0f;
    }
}

extern "C" void kernel_launch(void* const* d_in, const int* in_sizes, int n_in,
                              void* d_out, int out_size, void* d_ws, size_t ws_size,
                              hipStream_t stream)
{
    const float* q  = (const float*)d_in[0];
    const float* cb = (const float*)d_in[1];
    float* out = (float*)d_out;

    float* emb = out;                     // [B,D,H,W]
    float* yf  = out + Y_OFF;             // [B,H,W] as float
    float* rep = out + REP_OFF;           // [B,H,W,K]
    float* sc  = out + LOSS_OFF;          // loss, Hy, Hyx

    float* w       = (float*)d_ws;
    int*   hist    = (int*)w;             // 256 ints
    float* partial = w + 256;             // 2048 floats
    float* c2t     = w + 256 + 2048;      // 256 floats

    vq_prep_kernel<<<1, 256, 0, stream>>>(cb, c2t, hist);
    vq_fused_kernel<<<NBLK, 256, 0, stream>>>(q, cb, c2t, emb, yf, rep, hist, partial);
    vq_final_kernel<<<1, 256, 0, stream>>>(partial, hist, sc);
}

// Round 8
// 123.143 us; speedup vs baseline: 1.3092x; 1.0993x over previous
//
#include <hip/hip_runtime.h>

#define DD 8
#define HW 16384
#define KK 256
#define NPIX 524288
#define NBLK 1024                      // 512 px per block, 2 px/thread (A/B halves)

#define Y_OFF    4194304UL             // B*D*H*W
#define REP_OFF  4718592UL             // + B*H*W
#define LOSS_OFF 138936320UL           // + B*H*W*K

typedef float f4 __attribute__((ext_vector_type(4)));

// ---- fused: pipelined A/B — compute B while streaming A's folded one-hot rows ----
__global__ __launch_bounds__(256) void vq_fused_kernel(
    const float* __restrict__ q, const float* __restrict__ cb,
    float* __restrict__ emb, float* __restrict__ yf, float* __restrict__ rep,
    int* __restrict__ hist, float* __restrict__ partial)
{
    __shared__ float sc2[KK];
    __shared__ int   syA[256];
    __shared__ int   syB[256];
    __shared__ int   shist[KK];
    __shared__ float swred[4];

    const int tid  = threadIdx.x;
    const int wid  = tid >> 6;
    const int lane = tid & 63;
    shist[tid] = 0;

    {   // ||c||^2 in-block (same expression/bits as before)
        const f4 c01 = *(const f4*)(cb + tid*8);
        const f4 c23 = *(const f4*)(cb + tid*8 + 4);
        sc2[tid] = ((c01.x*c01.x + c01.y*c01.y) + (c01.z*c01.z + c01.w*c01.w))
                 + ((c23.x*c23.x + c23.y*c23.y) + (c23.z*c23.z + c23.w*c23.w));
    }

    const int pixBase = blockIdx.x << 9;     // 512 consecutive pixels, one image
    const int b   = pixBase >> 14;
    const int hw0 = pixBase & (HW - 1);
    const int hwA = hw0 + tid;
    const int hwB2 = hw0 + 256 + tid;
    const float* qb = q + (size_t)b * (DD*HW);
    float* eb = emb + (size_t)b * (DD*HW);

    // load both pixels up front (B's latency hides under phase-1 compute)
    float xsA[DD], xsB[DD];
#pragma unroll
    for (int d = 0; d < DD; ++d) xsA[d] = qb[d*HW + hwA];
#pragma unroll
    for (int d = 0; d < DD; ++d) xsB[d] = qb[d*HW + hwB2];

    const float xnA = ((xsA[0]*xsA[0] + xsA[1]*xsA[1]) + (xsA[2]*xsA[2] + xsA[3]*xsA[3]))
                    + ((xsA[4]*xsA[4] + xsA[5]*xsA[5]) + (xsA[6]*xsA[6] + xsA[7]*xsA[7]));
    const float xnB = ((xsB[0]*xsB[0] + xsB[1]*xsB[1]) + (xsB[2]*xsB[2] + xsB[3]*xsB[3]))
                    + ((xsB[4]*xsB[4] + xsB[5]*xsB[5]) + (xsB[6]*xsB[6] + xsB[7]*xsB[7]));

    __syncthreads();   // sc2 + shist ready

    // ---- phase 1: argmax for pixel A (exact R4 arithmetic; strict < == ref) ----
    float bestA = 3.4e38f;
    int   yA    = 0;
#pragma unroll 4
    for (int k = 0; k < KK; ++k) {
        const f4 c01 = *(const f4*)(cb + (k << 3));   // lane-invariant -> s_load
        const f4 c23 = *(const f4*)(cb + (k << 3) + 4);
        const float c2k = sc2[k];
        float dot = 0.f;
        dot = fmaf(xsA[0], c01.x, dot);
        dot = fmaf(xsA[1], c01.y, dot);
        dot = fmaf(xsA[2], c01.z, dot);
        dot = fmaf(xsA[3], c01.w, dot);
        dot = fmaf(xsA[4], c23.x, dot);
        dot = fmaf(xsA[5], c23.y, dot);
        dot = fmaf(xsA[6], c23.z, dot);
        dot = fmaf(xsA[7], c23.w, dot);
        const float t = (xnA - 2.0f*dot) + c2k;
        if (t < bestA) { bestA = t; yA = k; }
    }

    float err = 0.f;
    {
        const f4 cy01 = *(const f4*)(cb + (yA << 3));
        const f4 cy23 = *(const f4*)(cb + (yA << 3) + 4);
        const float cyv[DD] = {cy01.x, cy01.y, cy01.z, cy01.w,
                               cy23.x, cy23.y, cy23.z, cy23.w};
#pragma unroll
        for (int d = 0; d < DD; ++d) {
            eb[d*HW + hwA] = cyv[d];
            const float dd = cyv[d] - xsA[d];
            err = fmaf(dd, dd, err);
        }
    }
    yf[pixBase + tid] = (float)yA;
    syA[tid] = yA;
    atomicAdd(&shist[yA], 1);

    __syncthreads();   // syA ready

    // ---- phase 2: argmax for pixel B, interleaved with A's folded row streaming ----
    float bestB = 3.4e38f;
    int   yB    = 0;
    f4* repA = (f4*)rep + (((size_t)(pixBase + (wid << 6))) << 6) + lane;
    const int b4 = lane << 2;
    for (int c = 0; c < 64; ++c) {
#pragma unroll
        for (int j = 0; j < 4; ++j) {
            const int k = (c << 2) + j;
            const f4 c01 = *(const f4*)(cb + (k << 3));
            const f4 c23 = *(const f4*)(cb + (k << 3) + 4);
            const float c2k = sc2[k];
            float dot = 0.f;
            dot = fmaf(xsB[0], c01.x, dot);
            dot = fmaf(xsB[1], c01.y, dot);
            dot = fmaf(xsB[2], c01.z, dot);
            dot = fmaf(xsB[3], c01.w, dot);
            dot = fmaf(xsB[4], c23.x, dot);
            dot = fmaf(xsB[5], c23.y, dot);
            dot = fmaf(xsB[6], c23.z, dot);
            dot = fmaf(xsB[7], c23.w, dot);
            const float t = (xnB - 2.0f*dot) + c2k;
            if (t < bestB) { bestB = t; yB = k; }
        }
        // stream one of A's rows (1.0 folded -> no scatter, no RMW, any order ok)
        const int ya = syA[(wid << 6) + c];      // wave-uniform LDS broadcast
        f4 v;
        v.x = (ya == b4    ) ? 1.0f : 0.0f;
        v.y = (ya == b4 + 1) ? 1.0f : 0.0f;
        v.z = (ya == b4 + 2) ? 1.0f : 0.0f;
        v.w = (ya == b4 + 3) ? 1.0f : 0.0f;
        __builtin_nontemporal_store(v, repA + ((size_t)c << 6));
    }

    {
        const f4 cy01 = *(const f4*)(cb + (yB << 3));
        const f4 cy23 = *(const f4*)(cb + (yB << 3) + 4);
        const float cyv[DD] = {cy01.x, cy01.y, cy01.z, cy01.w,
                               cy23.x, cy23.y, cy23.z, cy23.w};
#pragma unroll
        for (int d = 0; d < DD; ++d) {
            eb[d*HW + hwB2] = cyv[d];
            const float dd = cyv[d] - xsB[d];
            err = fmaf(dd, dd, err);
        }
    }
    yf[pixBase + 256 + tid] = (float)yB;
    syB[tid] = yB;
    atomicAdd(&shist[yB], 1);

    // deterministic wave reduction of err (both pixels)
#pragma unroll
    for (int off = 32; off; off >>= 1)
        err += __shfl_down(err, off, 64);
    if (lane == 0) swred[wid] = err;

    __syncthreads();   // syB, shist, swred ready

    if (tid == 0)
        partial[blockIdx.x] = (swred[0] + swred[1]) + (swred[2] + swred[3]);
    atomicAdd(&hist[tid], shist[tid]);

    // ---- phase 3: stream B's folded rows (tight, store-bound) ----
    f4* repB = (f4*)rep + (((size_t)(pixBase + 256 + (wid << 6))) << 6) + lane;
    for (int s = 0; s < 64; ++s) {
        const int yb2 = syB[(wid << 6) + s];
        f4 v;
        v.x = (yb2 == b4    ) ? 1.0f : 0.0f;
        v.y = (yb2 == b4 + 1) ? 1.0f : 0.0f;
        v.z = (yb2 == b4 + 2) ? 1.0f : 0.0f;
        v.w = (yb2 == b4 + 3) ? 1.0f : 0.0f;
        __builtin_nontemporal_store(v, repB + ((size_t)s << 6));
    }
}

// ---------------- finalize scalars ----------------
__global__ __launch_bounds__(256) void vq_final_kernel(
    const float* __restrict__ partial, const int* __restrict__ hist,
    float* __restrict__ outp)
{
    const int tid = threadIdx.x;
    __shared__ double sred[4];
    __shared__ double shy[4];

    double s = 0.0;
#pragma unroll
    for (int i = 0; i < 4; ++i) s += (double)partial[tid + (i << 8)];
#pragma unroll
    for (int off = 32; off; off >>= 1)
        s += __shfl_down(s, off, 64);
    if ((tid & 63) == 0) sred[tid >> 6] = s;

    float c  = (float)hist[tid];
    float py = c * (1.0f / 524288.0f);
    double ht = (double)(py * log2f(py + 1e-10f));
#pragma unroll
    for (int off = 32; off; off >>= 1)
        ht += __shfl_down(ht, off, 64);
    if ((tid & 63) == 0) shy[tid >> 6] = ht;
    __syncthreads();

    if (tid == 0) {
        double S  = (sred[0] + sred[1]) + (sred[2] + sred[3]);
        double Hy = (shy[0]  + shy[1])  + (shy[2]  + shy[3]);
        // loss = 0.5*(0.25*S/4096 + S/4096) = 0.625 * S / 4096
        outp[0] = (float)(0.625 * S / 4096.0);
        outp[1] = (float)(-Hy);
        outp[2] = 0.0f;
    }
}

extern "C" void kernel_launch(void* const* d_in, const int* in_sizes, int n_in,
                              void* d_out, int out_size, void* d_ws, size_t ws_size,
                              hipStream_t stream)
{
    const float* q  = (const float*)d_in[0];
    const float* cb = (const float*)d_in[1];
    float* out = (float*)d_out;

    float* emb = out;                     // [B,D,H,W]
    float* yf  = out + Y_OFF;             // [B,H,W] as float
    float* rep = out + REP_OFF;           // [B,H,W,K]
    float* sc  = out + LOSS_OFF;          // loss, Hy, Hyx

    float* w       = (float*)d_ws;
    int*   hist    = (int*)w;             // 256 ints
    float* partial = w + 256;             // 1024 floats

    hipMemsetAsync(hist, 0, 1024, stream);   // zero hist
    vq_fused_kernel<<<NBLK, 256, 0, stream>>>(q, cb, emb, yf, rep, hist, partial);
    vq_final_kernel<<<1, 256, 0, stream>>>(partial, hist, sc);
}